// Round 1
// baseline (1086.253 us; speedup 1.0000x reference)
//
#include <hip/hip_runtime.h>
#include <stdint.h>

// out[16384,16] = x[16384,8192] @ W[8192,16], fp32. Memory-bound: x = 512 MiB
// read-once => roofline ~85-90 us at 6.3 TB/s. Design vs previous version:
//  - x is now DOUBLE-BUFFERED in registers (prefetch tile i+1 during compute of
//    tile i) so the compute phase has zero vmcnt waits; previous version stalled
//    a full HBM latency on x every tile.
//  - RPW 8->4 (acc 128->64 VGPRs) + __launch_bounds__(256,4): 4 blocks/CU
//    (16 waves/CU), grid 1024 = exactly 4/CU. Independent blocks stagger their
//    barrier drains so the CU always has loads in flight.
//  - W staged via __builtin_amdgcn_global_load_lds width=16 (no VGPR roundtrip,
//    no ds_writes). LDS dest is linear (HW requirement); the bank-swizzle is
//    applied by permuting the per-lane GLOBAL source address (same XOR
//    involution), and reads use the same swizzle => bit-identical LDS contents
//    to the verified previous kernel.

#define BATCH      16384
#define K_DIM      8192
#define OUT_DIM    16
#define KT         256                  // k's per LDS tile
#define NT         (K_DIM / KT)         // 32 tiles (even)
#define RPW        4                    // rows per wave
#define RPB        16                   // rows per block (4 waves * 4)

typedef float f32x4 __attribute__((ext_vector_type(4)));
typedef __attribute__((address_space(3))) uint32_t       lds_u32_t;
typedef __attribute__((address_space(1))) const uint32_t glb_u32_t;

__global__ __launch_bounds__(256, 4)
void NN_48696339202344_kernel(const float* __restrict__ x,
                              const float* __restrict__ W,
                              float* __restrict__ out) {
    // 2 buffers * 1024 chunks * 16B = 32 KB  (4 blocks/CU -> 128 KB <= 160 KB)
    __shared__ f32x4 lds[2 * 1024];

    const int u    = threadIdx.x;   // 0..255
    const int wave = u >> 6;        // 0..3
    const int lane = u & 63;        // 0..63
    const int rb   = blockIdx.x * RPB + wave * RPW;  // this wave's first row

    const f32x4* __restrict__ Wv = (const f32x4*)W;  // 32768 16B chunks

    // Pre-inverse-swizzled source chunk index for each of the 4 staging issues.
    // Dest chunk within tile: p = q*256 + u (linear, as global_load_lds writes
    // wave-uniform base + lane*16). Content wanted at pos p is chunk
    // p ^ ((p>>4)&7)  (XOR is an involution; >>4 bits unaffected by the XOR).
    int msrc[4];
    #pragma unroll
    for (int q = 0; q < 4; ++q) {
        const int p = q * 256 + u;
        msrc[q] = p ^ ((p >> 4) & 7);
    }

    float acc[RPW][OUT_DIM];
    #pragma unroll
    for (int r = 0; r < RPW; ++r)
        #pragma unroll
        for (int o = 0; o < OUT_DIM; ++o) acc[r][o] = 0.f;

    // Per-row x base pointers (lane offset folded in).
    const float* xrow[RPW];
    #pragma unroll
    for (int r = 0; r < RPW; ++r)
        xrow[r] = x + (size_t)(rb + r) * K_DIM + 4 * lane;

    // ---- helpers ----
    auto stageW = [&](int tile, int buf) {
        #pragma unroll
        for (int q = 0; q < 4; ++q) {
            __builtin_amdgcn_global_load_lds(
                (glb_u32_t*)(Wv + tile * 1024 + msrc[q]),
                (lds_u32_t*)(lds + buf * 1024 + q * 256 + wave * 64),
                16, 0, 0);
        }
    };

    auto loadX = [&](f32x4* dst, int tile) {
        #pragma unroll
        for (int r = 0; r < RPW; ++r)
            dst[r] = __builtin_nontemporal_load(
                         (const f32x4*)(xrow[r] + tile * KT));
    };

    auto compute = [&](const f32x4* __restrict__ buf, const f32x4* xv) {
        #pragma unroll
        for (int j = 0; j < 4; ++j) {
            const int kl = 4 * lane + j;            // k within tile
            f32x4 w4[4];
            #pragma unroll
            for (int c = 0; c < 4; ++c) {
                const int m   = kl * 4 + c;
                const int pos = m ^ ((m >> 4) & 7); // bank swizzle (read side)
                w4[c] = buf[pos];
            }
            const float* wf = (const float*)w4;     // W[kl][0..15]
            #pragma unroll
            for (int r = 0; r < RPW; ++r) {
                const float xs = xv[r][j];
                #pragma unroll
                for (int o = 0; o < OUT_DIM; ++o)
                    acc[r][o] = fmaf(xs, wf[o], acc[r][o]);
            }
        }
    };

    // ---- prologue: stage tile 0 (W -> buf0, x -> xA) ----
    f32x4 xA[RPW], xB[RPW];
    stageW(0, 0);
    loadX(xA, 0);
    __syncthreads();   // drains the DMA + x loads

    // ---- main loop: 2 tiles per iteration, ping-pong both W-LDS and x-regs ----
    for (int i = 0; i < NT; i += 2) {
        // half A: compute tile i from (buf0, xA); prefetch tile i+1 -> (buf1, xB)
        stageW(i + 1, 1);                 // i+1 <= 31 always (NT even)
        loadX(xB, i + 1);
        compute(lds, xA);
        __syncthreads();

        // half B: compute tile i+1 from (buf1, xB); prefetch tile i+2 -> (buf0, xA)
        if (i + 2 < NT) {
            stageW(i + 2, 0);
            loadX(xA, i + 2);
        }
        compute(lds + 1024, xB);
        __syncthreads();
    }

    // ---- epilogue: reduce 64 values (4 rows x 16 outs) across 64 lanes ----
    float vals[64];
    #pragma unroll
    for (int r = 0; r < RPW; ++r)
        #pragma unroll
        for (int o = 0; o < OUT_DIM; ++o)
            vals[r * 16 + o] = acc[r][o];

    // bisection reduce: after all steps, lane l holds total of value l
    #pragma unroll
    for (int d = 32; d >= 1; d >>= 1) {
        const bool hi = (lane & d) != 0;
        #pragma unroll
        for (int idx = 0; idx < d; ++idx) {
            const float keep = hi ? vals[idx + d] : vals[idx];
            const float send = hi ? vals[idx]     : vals[idx + d];
            const float recv = __shfl_xor(send, d, 64);
            vals[idx] = keep + recv;
        }
    }
    // rows rb..rb+3: out index = rb*16 + lane (coalesced 256B per wave)
    out[(size_t)rb * OUT_DIM + lane] = vals[0];
}

extern "C" void kernel_launch(void* const* d_in, const int* in_sizes, int n_in,
                              void* d_out, int out_size, void* d_ws, size_t ws_size,
                              hipStream_t stream) {
    const float* x = (const float*)d_in[0];
    const float* W = (const float*)d_in[1];
    float* out     = (float*)d_out;
    dim3 grid(BATCH / RPB);   // 1024 blocks = exactly 4 per CU
    dim3 block(256);
    NN_48696339202344_kernel<<<grid, block, 0, stream>>>(x, W, out);
}

// Round 2
// 671.281 us; speedup vs baseline: 1.6182x; 1.6182x over previous
//
#include <hip/hip_runtime.h>
#include <stdint.h>

// out[16384,16] = x[16384,8192] @ W[8192,16], fp32. Memory-bound: x = 512 MiB
// read-once => roofline ~85-90 us at 6.3 TB/s achievable.
//
// Round-1 post-mortem: __launch_bounds__(256,4) capped VGPRs at 64 (=256/4),
// kernel needs ~120 -> in-loop scratch spills: WRITE_SIZE 1.29 GB (out is 1 MB),
// FETCH 1.04 GB (x is 0.51 GB). ~1.8 GB parasitic traffic = the whole overage.
//
// Round-2 fix: same structure, but FIT IN REGISTERS.
//  - __launch_bounds__(256, 2): cap >=128 under either interpretation of arg2.
//    At VGPR<=128 the HW still runs 4 blocks/CU (16 waves/CU) since LDS=32KB
//    allows 5 blocks — we keep the occupancy without the spill-inducing cap.
//  - Inner loop consumes each W float4 immediately (4 live W regs, not 16),
//    giving the allocator an easy <=120-reg schedule under the 128 cap.
//  - x stays register-double-buffered (prefetch tile i+1 during compute of i);
//    W stays global_load_lds width=16 with XOR-swizzled SOURCE addresses
//    (linear LDS dest as HW requires) + same XOR on the read side.

#define BATCH      16384
#define K_DIM      8192
#define OUT_DIM    16
#define KT         256                  // k's per LDS tile
#define NT         (K_DIM / KT)         // 32 tiles (even)
#define RPW        4                    // rows per wave
#define RPB        16                   // rows per block (4 waves * 4)

typedef float f32x4 __attribute__((ext_vector_type(4)));
typedef __attribute__((address_space(3))) uint32_t       lds_u32_t;
typedef __attribute__((address_space(1))) const uint32_t glb_u32_t;

__global__ __launch_bounds__(256, 2)
void NN_48696339202344_kernel(const float* __restrict__ x,
                              const float* __restrict__ W,
                              float* __restrict__ out) {
    // 2 buffers * 1024 chunks * 16B = 32 KB
    __shared__ f32x4 lds[2 * 1024];

    const int u    = threadIdx.x;   // 0..255
    const int wave = u >> 6;        // 0..3
    const int lane = u & 63;        // 0..63
    const int rb   = blockIdx.x * RPB + wave * RPW;  // this wave's first row

    const f32x4* __restrict__ Wv = (const f32x4*)W;  // 32768 16B chunks

    float acc[RPW][OUT_DIM];
    #pragma unroll
    for (int r = 0; r < RPW; ++r)
        #pragma unroll
        for (int o = 0; o < OUT_DIM; ++o) acc[r][o] = 0.f;

    // Per-row x base pointers (lane offset folded in).
    const float* xrow[RPW];
    #pragma unroll
    for (int r = 0; r < RPW; ++r)
        xrow[r] = x + (size_t)(rb + r) * K_DIM + 4 * lane;

    // ---- helpers ----
    // Stage W tile -> LDS buffer. Dest is linear (global_load_lds writes
    // wave-uniform base + lane*16); content wanted at dest chunk p is global
    // chunk p ^ ((p>>4)&7) (XOR involution; the >>4 bits are unaffected).
    auto stageW = [&](int tile, int buf) {
        #pragma unroll
        for (int q = 0; q < 4; ++q) {
            const int p = q * 256 + u;
            const int msrc = p ^ ((p >> 4) & 7);
            __builtin_amdgcn_global_load_lds(
                (glb_u32_t*)(Wv + tile * 1024 + msrc),
                (lds_u32_t*)(lds + buf * 1024 + q * 256 + wave * 64),
                16, 0, 0);
        }
    };

    auto loadX = [&](f32x4* dst, int tile) {
        #pragma unroll
        for (int r = 0; r < RPW; ++r)
            dst[r] = __builtin_nontemporal_load(
                         (const f32x4*)(xrow[r] + tile * KT));
    };

    // Compute one tile. W fragments consumed immediately per 16B chunk so only
    // 4 W regs are live at a time (register-pressure insurance under the cap).
    auto compute = [&](const f32x4* __restrict__ buf, const f32x4* xv) {
        #pragma unroll
        for (int j = 0; j < 4; ++j) {
            const int kl = 4 * lane + j;            // k within tile
            float xs[RPW];
            #pragma unroll
            for (int r = 0; r < RPW; ++r) xs[r] = xv[r][j];
            #pragma unroll
            for (int c = 0; c < 4; ++c) {
                const int m   = kl * 4 + c;
                const int pos = m ^ ((m >> 4) & 7); // bank swizzle (read side)
                const f32x4 wc = buf[pos];          // W[kl][4c..4c+3]
                #pragma unroll
                for (int r = 0; r < RPW; ++r)
                    #pragma unroll
                    for (int oo = 0; oo < 4; ++oo)
                        acc[r][c * 4 + oo] = fmaf(xs[r], wc[oo], acc[r][c * 4 + oo]);
            }
        }
    };

    // ---- prologue: stage tile 0 (W -> buf0, x -> xA) ----
    f32x4 xA[RPW], xB[RPW];
    stageW(0, 0);
    loadX(xA, 0);
    __syncthreads();   // drains the DMA + x loads

    // ---- main loop: 2 tiles per iteration, ping-pong both W-LDS and x-regs ----
    for (int i = 0; i < NT; i += 2) {
        // half A: compute tile i from (buf0, xA); prefetch tile i+1 -> (buf1, xB)
        stageW(i + 1, 1);                 // i+1 <= 31 always (NT even)
        loadX(xB, i + 1);
        compute(lds, xA);
        __syncthreads();

        // half B: compute tile i+1 from (buf1, xB); prefetch tile i+2 -> (buf0, xA)
        if (i + 2 < NT) {
            stageW(i + 2, 0);
            loadX(xA, i + 2);
        }
        compute(lds + 1024, xB);
        __syncthreads();
    }

    // ---- epilogue: reduce 64 values (4 rows x 16 outs) across 64 lanes ----
    float vals[64];
    #pragma unroll
    for (int r = 0; r < RPW; ++r)
        #pragma unroll
        for (int o = 0; o < OUT_DIM; ++o)
            vals[r * 16 + o] = acc[r][o];

    // bisection reduce: after all steps, lane l holds total of value l
    #pragma unroll
    for (int d = 32; d >= 1; d >>= 1) {
        const bool hi = (lane & d) != 0;
        #pragma unroll
        for (int idx = 0; idx < d; ++idx) {
            const float keep = hi ? vals[idx + d] : vals[idx];
            const float send = hi ? vals[idx]     : vals[idx + d];
            const float recv = __shfl_xor(send, d, 64);
            vals[idx] = keep + recv;
        }
    }
    // rows rb..rb+3: out index = rb*16 + lane (coalesced 256B per wave)
    out[(size_t)rb * OUT_DIM + lane] = vals[0];
}

extern "C" void kernel_launch(void* const* d_in, const int* in_sizes, int n_in,
                              void* d_out, int out_size, void* d_ws, size_t ws_size,
                              hipStream_t stream) {
    const float* x = (const float*)d_in[0];
    const float* W = (const float*)d_in[1];
    float* out     = (float*)d_out;
    dim3 grid(BATCH / RPB);   // 1024 blocks = 4 per CU
    dim3 block(256);
    NN_48696339202344_kernel<<<grid, block, 0, stream>>>(x, W, out);
}